// Round 5
// baseline (486.494 us; speedup 1.0000x reference)
//
#include <hip/hip_runtime.h>

#define B_    256
#define N_    256
#define DIN   768
#define DOUT  300
#define DOUTP 320           // padded to 20*16
#define M_    (B_*N_)       // 65536
#define HP_ELEMS (M_*DOUT)  // 19660800
#define NEG_INF -9.0e15f

typedef _Float16 f16;
typedef __attribute__((ext_vector_type(8))) _Float16 f16x8;
typedef __attribute__((ext_vector_type(4))) _Float16 f16x4;
typedef __attribute__((ext_vector_type(4))) float    f32x4;

// ---- kernel 0: WtT[kt][n][k'] = f16(W[kt*32+k'][n]), linear, pad n>=300 ----
__global__ __launch_bounds__(256) void prep_wt(const float* __restrict__ W,
                                               f16* __restrict__ WtT) {
    int idx = blockIdx.x * 256 + threadIdx.x;      // over DIN*DOUTP
    if (idx >= DIN * DOUTP) return;
    int k = idx / DOUTP, n = idx - k * DOUTP;
    float v = (n < DOUT) ? W[k * DOUT + n] : 0.0f;
    WtT[(((size_t)(k >> 5) * DOUTP + n) << 5) + (k & 31)] = (f16)v;
}

// ---- kernel 1: Wh = h@W + pos; f_src/f_dst; WhT2 ---------------------------
// grid 1024 strips of 64 rows, 256 threads (4 waves), ZERO K-loop barriers,
// ZERO K-loop LDS. A-fragments load f32 direct from h (8 consecutive floats
// per lane), convert in-reg; B-fragments from L2-resident WtT. Both
// double-buffered; compiler emits precise counted s_waitcnt (no asm).
// WhT2 layout [bidx][kt][g=k'/4][col][4] -> full-line coalesced stores.
__global__ __launch_bounds__(256, 2) void gemm1(
    const float* __restrict__ h, const f16* __restrict__ WtT,
    const int* __restrict__ positions,
    const float* __restrict__ a_src, const float* __restrict__ a_dst,
    const float* __restrict__ pos_table,
    f16* __restrict__ WhT2, float* __restrict__ f_src, float* __restrict__ f_dst)
{
    __shared__ float pfs[64][4], pfd[64][4];

    const int tid  = threadIdx.x;
    const int wave = tid >> 6, lane = tid & 63;
    const int quad = lane >> 4, c = lane & 15;
    const int rowbase = blockIdx.x * 64;

    // per-lane A base pointers: h[rowbase + rt*16 + c][quad*8]
    const float* ab0 = h + (size_t)(rowbase + c) * DIN + quad * 8;
    const float* ab1 = ab0 + 16 * DIN;
    const float* ab2 = ab0 + 32 * DIN;
    const float* ab3 = ab0 + 48 * DIN;

    int boffs[5];
#pragma unroll
    for (int i = 0; i < 5; ++i) {
        int n = (wave * 5 + i) * 16 + c;
        boffs[i] = (n << 5) + (quad << 3);
    }

    f32x4 acc[4][5];
#pragma unroll
    for (int rt = 0; rt < 4; ++rt)
#pragma unroll
        for (int i = 0; i < 5; ++i) acc[rt][i] = (f32x4){0.f, 0.f, 0.f, 0.f};

    float4 av[2][4][2];   // [buf][row-tile][16B half] — static-indexed only
    f16x8  bs[2][5];
    f16x8  af[4];

#define LOADA(KT, S) do {                                                      \
    av[S][0][0] = *(const float4*)(ab0 + (KT) * 32);                           \
    av[S][0][1] = *(const float4*)(ab0 + (KT) * 32 + 4);                       \
    av[S][1][0] = *(const float4*)(ab1 + (KT) * 32);                           \
    av[S][1][1] = *(const float4*)(ab1 + (KT) * 32 + 4);                       \
    av[S][2][0] = *(const float4*)(ab2 + (KT) * 32);                           \
    av[S][2][1] = *(const float4*)(ab2 + (KT) * 32 + 4);                       \
    av[S][3][0] = *(const float4*)(ab3 + (KT) * 32);                           \
    av[S][3][1] = *(const float4*)(ab3 + (KT) * 32 + 4);                       \
} while (0)

#define LOADB(KT, S) do {                                                      \
    const f16* p_ = WtT + (size_t)(KT) * (DOUTP * 32);                         \
    _Pragma("unroll")                                                          \
    for (int i_ = 0; i_ < 5; ++i_)                                             \
        bs[S][i_] = *(const f16x8*)(p_ + boffs[i_]);                           \
} while (0)

#define CVT(S) do {                                                            \
    _Pragma("unroll")                                                          \
    for (int rt_ = 0; rt_ < 4; ++rt_) {                                        \
        float4 u0 = av[S][rt_][0], u1 = av[S][rt_][1];                         \
        af[rt_] = (f16x8){(f16)u0.x, (f16)u0.y, (f16)u0.z, (f16)u0.w,          \
                          (f16)u1.x, (f16)u1.y, (f16)u1.z, (f16)u1.w};         \
    } } while (0)

#define COMP(S) do {                                                           \
    __builtin_amdgcn_s_setprio(1);                                             \
    _Pragma("unroll")                                                          \
    for (int rt_ = 0; rt_ < 4; ++rt_)                                          \
        _Pragma("unroll")                                                      \
        for (int i_ = 0; i_ < 5; ++i_)                                         \
            acc[rt_][i_] = __builtin_amdgcn_mfma_f32_16x16x32_f16(             \
                af[rt_], bs[S][i_], acc[rt_][i_], 0, 0, 0);                    \
    __builtin_amdgcn_s_setprio(0);                                             \
} while (0)

    LOADA(0, 0);
    LOADB(0, 0);
#pragma unroll
    for (int kt = 0; kt < 24; ++kt) {
        if (kt + 1 < 24) {
            LOADA(kt + 1, (kt + 1) & 1);
            LOADB(kt + 1, (kt + 1) & 1);
        }
        CVT(kt & 1);
        COMP(kt & 1);
    }
#undef COMP
#undef CVT
#undef LOADB
#undef LOADA

    // ---- epilogue: pos add, f_src/f_dst, WhT2 store (full-line layout) ----
    const int bidx = rowbase >> 8;
    const int ktb0 = (rowbase & 255) >> 5;       // 64 rows span 2 k-tiles

    int posr[4][4];
#pragma unroll
    for (int rt = 0; rt < 4; ++rt)
#pragma unroll
        for (int r = 0; r < 4; ++r)
            posr[rt][r] = positions[rowbase + rt * 16 + quad * 4 + r];

    float fs[4][4], fd[4][4];
#pragma unroll
    for (int rt = 0; rt < 4; ++rt)
#pragma unroll
        for (int r = 0; r < 4; ++r) { fs[rt][r] = 0.f; fd[rt][r] = 0.f; }

#pragma unroll
    for (int i = 0; i < 5; ++i) {
        int col = (wave * 5 + i) * 16 + c;
        if (col < DOUT) {
            float as = a_src[col], ad = a_dst[col];
#pragma unroll
            for (int rt = 0; rt < 4; ++rt)
#pragma unroll
                for (int r = 0; r < 4; ++r) {
                    float v = acc[rt][i][r] + pos_table[posr[rt][r] * DOUT + col];
                    acc[rt][i][r] = v;
                    fs[rt][r] += v * as;
                    fd[rt][r] += v * ad;
                }
        } else {
#pragma unroll
            for (int rt = 0; rt < 4; ++rt)
#pragma unroll
                for (int r = 0; r < 4; ++r) acc[rt][i][r] = 0.0f;
        }
    }
#pragma unroll
    for (int off = 1; off < 16; off <<= 1) {
#pragma unroll
        for (int rt = 0; rt < 4; ++rt)
#pragma unroll
            for (int r = 0; r < 4; ++r) {
                fs[rt][r] += __shfl_xor(fs[rt][r], off, 16);
                fd[rt][r] += __shfl_xor(fd[rt][r], off, 16);
            }
    }
    if (c == 0) {
#pragma unroll
        for (int rt = 0; rt < 4; ++rt)
#pragma unroll
            for (int r = 0; r < 4; ++r) {
                int row = rt * 16 + quad * 4 + r;
                pfs[row][wave] = fs[rt][r];
                pfd[row][wave] = fd[rt][r];
            }
    }
    // WhT2[bidx][kt][g][col][4]: g = (k' >> 2); per-instruction stores are
    // 4 x 128B fully-covered segments (no partial-line write amplification).
#pragma unroll
    for (int i = 0; i < 5; ++i) {
        int col = (wave * 5 + i) * 16 + c;
#pragma unroll
        for (int rt = 0; rt < 4; ++rt) {
            f16x4 u = (f16x4){(f16)acc[rt][i][0], (f16)acc[rt][i][1],
                              (f16)acc[rt][i][2], (f16)acc[rt][i][3]};
            size_t off = (((size_t)(bidx * 8 + ktb0 + (rt >> 1)) * 8
                           + (rt & 1) * 4 + quad) * DOUTP + col) * 4;
            *(f16x4*)(WhT2 + off) = u;
        }
    }
    __syncthreads();
    if (tid < 64) {
        f_src[rowbase + tid] = pfs[tid][0] + pfs[tid][1] + pfs[tid][2] + pfs[tid][3];
        f_dst[rowbase + tid] = pfd[tid][0] + pfd[tid][1] + pfd[tid][2] + pfd[tid][3];
    }
}

// ---- kernel 2: fused masked-softmax + h_prime = att @ Wh ------------------
// grid 1024 (64 rows/block), 256 threads. P in swizzled LDS; B fragments
// direct global->reg from WhT2 (two f16x4 per fragment), double-buffered;
// single barrier total.
__global__ __launch_bounds__(256, 3) void fused2(
    const float* __restrict__ adj, const float* __restrict__ f_src,
    const float* __restrict__ f_dst, const f16* __restrict__ WhT2,
    float* __restrict__ att, float* __restrict__ hp)
{
    __shared__ f16 Pl[64 * 256];        // 32 KB, XOR-swizzled

    const int tid  = threadIdx.x;
    const int wave = tid >> 6, lane = tid & 63;
    const int quad = lane >> 4, c = lane & 15;
    const int rowbase = blockIdx.x * 64;
    const int bidx = rowbase >> 8;
    const int cx7 = c & 7;

    const f16* wbase = WhT2 + (size_t)bidx * 8 * (DOUTP * 32);

    f16x8 bs[2][5];
#define PREF2(KT, S) do {                                                      \
    const f16* p_ = wbase + (size_t)(KT) * (DOUTP * 32);                       \
    _Pragma("unroll")                                                          \
    for (int i_ = 0; i_ < 5; ++i_) {                                           \
        int n_ = (wave * 5 + i_) * 16 + c;                                     \
        f16x4 lo_ = *(const f16x4*)(p_ + (2 * quad) * (DOUTP * 4) + n_ * 4);   \
        f16x4 hi_ = *(const f16x4*)(p_ + (2 * quad + 1) * (DOUTP * 4) + n_ * 4); \
        bs[S][i_] = (f16x8){lo_[0], lo_[1], lo_[2], lo_[3],                    \
                            hi_[0], hi_[1], hi_[2], hi_[3]};                   \
    } } while (0)

    // ---- phase 0: masked softmax for 64 rows; att out + P into LDS ----
    {
        float4 fd4 = *(const float4*)(f_dst + bidx * N_ + lane * 4);
        const float* arow = adj + (size_t)(rowbase + wave * 16) * N_ + lane * 4;
        float4 nx0 = *(const float4*)arow;
        float4 nx1 = *(const float4*)(arow + N_);
        for (int rr = 0; rr < 16; ++rr) {
            float4 a4 = nx0;
            nx0 = nx1;
            if (rr + 2 < 16) nx1 = *(const float4*)(arow + (size_t)(rr + 2) * N_);
            const int lrow = wave * 16 + rr;
            const int row  = rowbase + lrow;
            float fsv = f_src[row];

            float v, e0, e1, e2, e3;
            v = fsv + fd4.x; v = v >= 0.f ? v : 0.2f * v; e0 = a4.x > 0.f ? v : NEG_INF;
            v = fsv + fd4.y; v = v >= 0.f ? v : 0.2f * v; e1 = a4.y > 0.f ? v : NEG_INF;
            v = fsv + fd4.z; v = v >= 0.f ? v : 0.2f * v; e2 = a4.z > 0.f ? v : NEG_INF;
            v = fsv + fd4.w; v = v >= 0.f ? v : 0.2f * v; e3 = a4.w > 0.f ? v : NEG_INF;

            float mx = fmaxf(fmaxf(e0, e1), fmaxf(e2, e3));
#pragma unroll
            for (int off = 1; off < 64; off <<= 1) mx = fmaxf(mx, __shfl_xor(mx, off, 64));

            float p0 = __expf(e0 - mx), p1 = __expf(e1 - mx);
            float p2 = __expf(e2 - mx), p3 = __expf(e3 - mx);
            float s = p0 + p1 + p2 + p3;
#pragma unroll
            for (int off = 1; off < 64; off <<= 1) s += __shfl_xor(s, off, 64);

            float inv = 1.0f / s;
            *(float4*)(att + (size_t)row * N_ + lane * 4) =
                make_float4(p0 * inv, p1 * inv, p2 * inv, p3 * inv);
            int slot = (lane >> 1) ^ (lrow & 7);
            *(f16x4*)&Pl[lrow * 256 + slot * 8 + (lane & 1) * 4] =
                (f16x4){(f16)(p0 * inv), (f16)(p1 * inv), (f16)(p2 * inv), (f16)(p3 * inv)};
        }
    }
    PREF2(0, 0);
    __syncthreads();   // P visible — the only barrier

    // ---- phase 1: GEMM, A = P (LDS), B reg double-buffer, no barriers ----
    f32x4 acc[4][5];
#pragma unroll
    for (int rt = 0; rt < 4; ++rt)
#pragma unroll
        for (int i = 0; i < 5; ++i) acc[rt][i] = (f32x4){0.f, 0.f, 0.f, 0.f};

#define COMPUTE2(KT, S) do {                                                   \
    const int k4_ = (KT) * 4 + quad;                                           \
    __builtin_amdgcn_s_setprio(1);                                             \
    _Pragma("unroll")                                                          \
    for (int rt_ = 0; rt_ < 4; ++rt_) {                                        \
        f16x8 af = *(const f16x8*)&Pl[(rt_ * 16 + c) * 256 + ((k4_ ^ cx7) << 3)]; \
        _Pragma("unroll")                                                      \
        for (int i_ = 0; i_ < 5; ++i_)                                         \
            acc[rt_][i_] = __builtin_amdgcn_mfma_f32_16x16x32_f16(             \
                af, bs[S][i_], acc[rt_][i_], 0, 0, 0);                         \
    }                                                                          \
    __builtin_amdgcn_s_setprio(0);                                             \
    } while (0)

#pragma unroll
    for (int kt2 = 0; kt2 < 4; ++kt2) {
        const int ktA = 2 * kt2, ktB = 2 * kt2 + 1;
        PREF2(ktB, 1);
        COMPUTE2(ktA, 0);
        if (ktB + 1 < 8) PREF2(ktB + 1, 0);
        COMPUTE2(ktB, 1);
    }
#undef COMPUTE2
#undef PREF2

    // epilogue: hp[row][col], col<300
#pragma unroll
    for (int i = 0; i < 5; ++i) {
        int col = (wave * 5 + i) * 16 + c;
        if (col < DOUT) {
#pragma unroll
            for (int rt = 0; rt < 4; ++rt) {
                int row0 = rowbase + rt * 16 + quad * 4;
#pragma unroll
                for (int r = 0; r < 4; ++r)
                    hp[(size_t)(row0 + r) * DOUT + col] = acc[rt][i][r];
            }
        }
    }
}

extern "C" void kernel_launch(void* const* d_in, const int* in_sizes, int n_in,
                              void* d_out, int out_size, void* d_ws, size_t ws_size,
                              hipStream_t stream)
{
    const float* h         = (const float*)d_in[0];
    const float* adj       = (const float*)d_in[1];
    const int*   positions = (const int*)d_in[2];
    const float* W         = (const float*)d_in[3];
    const float* a_src     = (const float*)d_in[4];
    const float* a_dst     = (const float*)d_in[5];
    const float* pos_table = (const float*)d_in[6];

    float* hp  = (float*)d_out;            // [65536][300]
    float* att = hp + HP_ELEMS;            // [65536][256]

    f16*   WtT   = (f16*)d_ws;                         // [24][320][32]
    f16*   WhT2  = WtT + (size_t)DOUTP * DIN;          // [256][8][8][320][4]
    float* f_src = (float*)(WhT2 + (size_t)B_ * DOUTP * N_);
    float* f_dst = f_src + M_;

    hipLaunchKernelGGL(prep_wt, dim3((DIN * DOUTP + 255) / 256), dim3(256), 0, stream, W, WtT);
    hipLaunchKernelGGL(gemm1,   dim3(M_ / 64), dim3(256), 0, stream,
                       h, WtT, positions, a_src, a_dst, pos_table, WhT2, f_src, f_dst);
    hipLaunchKernelGGL(fused2,  dim3(M_ / 64), dim3(256), 0, stream,
                       adj, f_src, f_dst, WhT2, att, hp);
}